// Round 7
// baseline (1054.116 us; speedup 1.0000x reference)
//
#include <hip/hip_runtime.h>
#include <stdint.h>

#define BB 256
#define TT 128
#define DD 512
#define HH 512
#define G4 2048      // 4H

typedef short bf16x8 __attribute__((ext_vector_type(8)));
typedef unsigned short u16x8 __attribute__((ext_vector_type(8)));
typedef float f32x4  __attribute__((ext_vector_type(4)));

__device__ __forceinline__ unsigned short f2bf(float f){
  union { float f; unsigned u; } v; v.f = f;
  unsigned u = v.u;
  unsigned r = (u + 0x7FFFu + ((u >> 16) & 1u)) >> 16;
  return (unsigned short)r;
}
__device__ __forceinline__ float sigf(float x){
  return __builtin_amdgcn_rcpf(1.0f + __expf(-x));
}
__device__ __forceinline__ float tanhfast(float x){
  return 1.0f - 2.0f*__builtin_amdgcn_rcpf(1.0f + __expf(2.0f*x));
}

// x [B,T,D] f32 -> xtr [T,B,D] bf16  (coalesced read and write)
__global__ void prep_x_k(const float* __restrict__ x, unsigned short* __restrict__ xtr){
  const int n4 = BB*TT*(DD/4);
  for (int i = blockIdx.x*blockDim.x + threadIdx.x; i < n4; i += gridDim.x*blockDim.x){
    int d4 = i & (DD/4 - 1);
    int b  = (i / (DD/4)) & (BB-1);
    int t  = i / ((DD/4)*BB);
    float4 v = *(const float4*)(x + (((size_t)b*TT + t)*DD + (size_t)d4*4));
    ushort4 o;
    o.x = f2bf(v.x); o.y = f2bf(v.y); o.z = f2bf(v.z); o.w = f2bf(v.w);
    *(ushort4*)(xtr + (((size_t)t*BB + b)*DD + (size_t)d4*4)) = o;
  }
}

// Combined W+U, fragment-packed for phase-2 B operand:
// upk[d][hb(32)][ks(32)][gf(4)][lane(64)][e(8)], k = ks*32 + (lane>>4)*8 + e
// ks<16 -> W[k][n], ks>=16 -> U[k-512][n];  n = gf*512 + hb*16 + (lane&15)
__global__ void prep_uw_k(const float* __restrict__ Wf, const float* __restrict__ Uf,
                          const float* __restrict__ Wb, const float* __restrict__ Ub,
                          unsigned short* __restrict__ upk){
  const int tot = 2*32*32*4*64*8;  // 4,194,304
  for (int i = blockIdx.x*blockDim.x + threadIdx.x; i < tot; i += gridDim.x*blockDim.x){
    int e    = i & 7;
    int lane = (i >> 3) & 63;
    int gf   = (i >> 9) & 3;
    int ks   = (i >> 11) & 31;
    int hb   = (i >> 16) & 31;
    int d    = (i >> 21) & 1;
    int jl = lane & 15, q = lane >> 4;
    int n = gf*HH + hb*16 + jl;
    int k = ks*32 + q*8 + e;
    float v;
    if (k < DD) v = (d ? Wb : Wf)[(size_t)k*G4 + n];
    else        v = (d ? Ub : Uf)[(size_t)(k-DD)*G4 + n];
    upk[i] = f2bf(v);
  }
}

// bias_pk[d][hb(32)][gf(4)][jl(16)]
__global__ void prep_bias_k(const float* __restrict__ bf_, const float* __restrict__ bb_,
                            float* __restrict__ bias_pk){
  int i = blockIdx.x*blockDim.x + threadIdx.x;
  if (i < 2*32*4*16){
    int jl = i & 15;
    int gf = (i >> 4) & 3;
    int hb = (i >> 6) & 31;
    int d  = i >> 11;
    const float* src = d ? bb_ : bf_;
    bias_pk[i] = src[gf*HH + hb*16 + jl];
  }
}

// Persistent fused LSTM. 256 blocks x 128 thr (2 waves x 32 rows), 1 block/CU
// (131072B LDS forces it), grid == CU count -> all blocks resident (regular
// launch; protocol uses only agent-scope flags, no grid.sync).
// g = bid&7 -> (d = g>>2, mq = g&3); hb = bid>>3 owns h-cols [hb*16, hb*16+16).
// W+U slice (128KB) resident in LDS in B-fragment order. Per step:
//   x-part MFMAs (K 0..511) BEFORE the flag gate (overlaps producers' latency),
//   poll 32 per-wave flags, h-part MFMAs (K 512..1023), epilogue, store+flag.
// Chain = (g, w): wave w depends only on wave w of the group's 32 blocks.
__global__ __launch_bounds__(128, 1)
void lstm_seq_k(const unsigned short* __restrict__ xtr,
                const unsigned short* __restrict__ upk,
                const float* __restrict__ bias_pk,
                unsigned short* hx,
                int* flags,
                float* __restrict__ out)
{
  __shared__ __align__(1024) unsigned short Ul[65536];  // 128KB: [ks32][gf4][lane64][8]

  const int tid  = threadIdx.x;
  const int lane = tid & 63;
  const int w    = tid >> 6;          // 0..1
  const int bid  = blockIdx.x;
  const int g    = bid & 7;
  const int hb   = bid >> 3;
  const int d    = g >> 2;
  const int mq   = g & 3;
  const int m0   = mq * 64;
  const int jl   = lane & 15, q = lane >> 4;

  // stage W+U slice (linear, fragment order — conflict-free ds_read_b128 later)
  const unsigned short* usrc = upk + (size_t)(d*32 + hb)*65536;
  for (int it = 0; it < 64; ++it){
    int u = it*128 + tid;
    __builtin_amdgcn_global_load_lds(
      (const __attribute__((address_space(1))) void*)(usrc + (size_t)u*8),
      (__attribute__((address_space(3))) void*)(Ul + u*8), 16, 0, 0);
  }

  float biasv[4];
  #pragma unroll
  for (int gf = 0; gf < 4; ++gf)
    biasv[gf] = bias_pk[((d*32 + hb)*4 + gf)*16 + jl];

  int* myflags = flags + (g*2 + w)*64;    // 32 words used per (g,w) chain
  float cst[2][4];
  #pragma unroll
  for (int a = 0; a < 2; ++a)
    #pragma unroll
    for (int b = 0; b < 4; ++b) cst[a][b] = 0.f;

  __syncthreads();   // weights staged (barrier drains vmcnt)

  for (int s = 0; s < TT; ++s){
    const int t = d ? (TT-1-s) : s;

    // ---- x A-fragments (plain loads, L2-shared within XCD group) ----
    const unsigned short* xb = xtr + ((size_t)t*BB + m0 + w*32)*DD;
    bf16x8 xa[2][16];
    #pragma unroll
    for (int ks = 0; ks < 16; ++ks)
      #pragma unroll
      for (int am = 0; am < 2; ++am)
        xa[am][ks] = *(const bf16x8*)(xb + (size_t)(am*16 + jl)*DD + ks*32 + q*8);

    // ---- acc init = bias ----
    f32x4 acc[2][4];
    #pragma unroll
    for (int am = 0; am < 2; ++am)
      #pragma unroll
      for (int gf = 0; gf < 4; ++gf){
        float bv = biasv[gf];
        acc[am][gf] = (f32x4){bv, bv, bv, bv};
      }

    // ---- x-part MFMAs (independent of recurrence — overlaps the wait) ----
    #pragma unroll
    for (int ks = 0; ks < 16; ++ks){
      #pragma unroll
      for (int gf = 0; gf < 4; ++gf){
        bf16x8 b = *(const bf16x8*)(Ul + ((ks*4 + gf)*64 + lane)*8);
        #pragma unroll
        for (int am = 0; am < 2; ++am)
          acc[am][gf] = __builtin_amdgcn_mfma_f32_16x16x32_bf16(xa[am][ks], b, acc[am][gf], 0, 0, 0);
      }
    }

    // ---- wait for the 32 producer-waves of this chain ----
    if (s > 0){
      for (;;){
        int v = (lane < 32)
          ? __hip_atomic_load(&myflags[lane], __ATOMIC_RELAXED, __HIP_MEMORY_SCOPE_AGENT)
          : s;
        if (__all(v >= s)) break;
        __builtin_amdgcn_s_sleep(1);
      }
    }
    asm volatile("" ::: "memory");

    // ---- h A-fragments (agent-scope loads, parity s&1) ----
    const unsigned short* hbase = hx + (((size_t)(g*2 + (s&1))*2 + w)*32)*2*256;
    union af_t { unsigned long long u[2]; bf16x8 v; } ha[2][16];
    #pragma unroll
    for (int ks = 0; ks < 16; ++ks){
      int hb2 = ks*2 + (q >> 1);
      #pragma unroll
      for (int am = 0; am < 2; ++am){
        const unsigned long long* p = (const unsigned long long*)
            (hbase + (size_t)(hb2*2 + am)*256 + jl*16 + (q&1)*8);
        ha[am][ks].u[0] = __hip_atomic_load(p,     __ATOMIC_RELAXED, __HIP_MEMORY_SCOPE_AGENT);
        ha[am][ks].u[1] = __hip_atomic_load(p + 1, __ATOMIC_RELAXED, __HIP_MEMORY_SCOPE_AGENT);
      }
    }

    // ---- h-part MFMAs ----
    #pragma unroll
    for (int ks = 0; ks < 16; ++ks){
      #pragma unroll
      for (int gf = 0; gf < 4; ++gf){
        bf16x8 b = *(const bf16x8*)(Ul + (((16 + ks)*4 + gf)*64 + lane)*8);
        #pragma unroll
        for (int am = 0; am < 2; ++am)
          acc[am][gf] = __builtin_amdgcn_mfma_f32_16x16x32_bf16(ha[am][ks].v, b, acc[am][gf], 0, 0, 0);
      }
    }

    // ---- epilogue: gates, c in regs, stores ----
    unsigned short* hw = hx + ((((size_t)(g*2 + ((s+1)&1))*2 + w)*32 + hb)*2)*256;
    #pragma unroll
    for (int am = 0; am < 2; ++am){
      #pragma unroll
      for (int rr = 0; rr < 4; ++rr){
        float zi = acc[am][0][rr];
        float zf = acc[am][1][rr];
        float zg = acc[am][2][rr];
        float zo = acc[am][3][rr];
        float i_ = sigf(zi);
        float f_ = sigf(zf);
        float g_ = tanhfast(zg);
        float o_ = sigf(zo);
        float c  = f_*cst[am][rr] + i_*g_;
        cst[am][rr] = c;
        float h = o_*tanhfast(c);

        int row = q*4 + rr;
        int b_  = m0 + w*32 + am*16 + row;
        out[((size_t)b_*TT + t)*(2*HH) + (size_t)d*HH + hb*16 + jl] = h;

        unsigned short h16 = f2bf(h);
        int other = __shfl_xor((int)h16, 1);
        if (!(jl & 1)){
          unsigned int pack = (unsigned int)h16 | (((unsigned int)other & 0xFFFFu) << 16);
          __hip_atomic_store((unsigned int*)(hw + am*256 + row*16 + (jl & ~1)),
                             pack, __ATOMIC_RELAXED, __HIP_MEMORY_SCOPE_AGENT);
        }
      }
    }

    asm volatile("s_waitcnt vmcnt(0)" ::: "memory");  // h stores at coherence point
    if (lane == 0)
      __hip_atomic_store(&myflags[hb], s + 1, __ATOMIC_RELAXED, __HIP_MEMORY_SCOPE_AGENT);
  }
}

// sent_emb[b][n] = word_emb[b][T-1][n] (n<H) or word_emb[b][0][n] (n>=H)
__global__ void final_k(float* __restrict__ out){
  int i = blockIdx.x*blockDim.x + threadIdx.x;
  if (i < BB*2*HH){
    int b = i >> 10;
    int n = i & 1023;
    int t = (n < HH) ? (TT-1) : 0;
    out[(size_t)BB*TT*2*HH + i] = out[((size_t)b*TT + t)*2*HH + n];
  }
}

extern "C" void kernel_launch(void* const* d_in, const int* in_sizes, int n_in,
                              void* d_out, int out_size, void* d_ws, size_t ws_size,
                              hipStream_t stream)
{
  const float* x   = (const float*)d_in[0];
  const float* Wf  = (const float*)d_in[1];
  const float* Uf  = (const float*)d_in[2];
  const float* bf_ = (const float*)d_in[3];
  const float* Wb  = (const float*)d_in[4];
  const float* Ub  = (const float*)d_in[5];
  const float* bb_ = (const float*)d_in[6];
  float* out = (float*)d_out;

  char* ws = (char*)d_ws;
  unsigned short* xtr  = (unsigned short*)(ws);              // 33,554,432 B
  unsigned short* upk  = (unsigned short*)(ws + 33554432);   //  8,388,608 B
  float* bias_pk       = (float*)(ws + 41943040);            //     16,384 B
  unsigned short* hx   = (unsigned short*)(ws + 41959424);   //  1,048,576 B
  int* flags           = (int*)(ws + 43008000);              //      4,096 B

  hipMemsetAsync(hx, 0, 1048576, stream);
  hipMemsetAsync(flags, 0, 4096, stream);

  prep_x_k   <<<2048, 256, 0, stream>>>(x, xtr);
  prep_uw_k  <<<2048, 256, 0, stream>>>(Wf, Uf, Wb, Ub, upk);
  prep_bias_k<<<16,   256, 0, stream>>>(bf_, bb_, bias_pk);

  // Regular launch (NOT cooperative): R6's silent-zero failure is consistent
  // with hipLaunchCooperativeKernel rejecting this config without our checking
  // the return code. The flag protocol never uses grid.sync; with 256 blocks,
  // 1 block/CU (LDS-forced) and 256 CUs, all blocks are co-resident.
  lstm_seq_k<<<256, 128, 0, stream>>>(xtr, upk, bias_pk, hx, flags, out);

  final_k<<<1024, 256, 0, stream>>>(out);
}

// Round 8
// 928.933 us; speedup vs baseline: 1.1348x; 1.1348x over previous
//
#include <hip/hip_runtime.h>
#include <stdint.h>

#define BB 256
#define TT 128
#define DD 512
#define HH 512
#define G4 2048      // 4H

typedef short bf16x8 __attribute__((ext_vector_type(8)));
typedef float f32x4  __attribute__((ext_vector_type(4)));
typedef int   i32x4  __attribute__((ext_vector_type(4)));

__device__ __forceinline__ unsigned short f2bf(float f){
  union { float f; unsigned u; } v; v.f = f;
  unsigned u = v.u;
  unsigned r = (u + 0x7FFFu + ((u >> 16) & 1u)) >> 16;
  return (unsigned short)r;
}
__device__ __forceinline__ float bf2f(unsigned short s){
  union { unsigned u; float f; } v; v.u = ((unsigned)s) << 16;
  return v.f;
}
__device__ __forceinline__ float sigf(float x){
  return __builtin_amdgcn_rcpf(1.0f + __expf(-x));
}
__device__ __forceinline__ float tanhfast(float x){
  return 1.0f - 2.0f*__builtin_amdgcn_rcpf(1.0f + __expf(2.0f*x));
}
__device__ __forceinline__ int packbf(float a, float b){
  return (int)f2bf(a) | ((int)f2bf(b) << 16);
}

// x [B,T,D] f32 -> xtr [T,B,D] bf16
__global__ void prep_x_k(const float* __restrict__ x, unsigned short* __restrict__ xtr){
  const int n4 = BB*TT*(DD/4);
  for (int i = blockIdx.x*blockDim.x + threadIdx.x; i < n4; i += gridDim.x*blockDim.x){
    int d4 = i & (DD/4 - 1);
    int b  = (i / (DD/4)) & (BB-1);
    int t  = i / ((DD/4)*BB);
    float4 v = *(const float4*)(x + (((size_t)b*TT + t)*DD + (size_t)d4*4));
    ushort4 o;
    o.x = f2bf(v.x); o.y = f2bf(v.y); o.z = f2bf(v.z); o.w = f2bf(v.w);
    *(ushort4*)(xtr + (((size_t)t*BB + b)*DD + (size_t)d4*4)) = o;
  }
}

// wupk[arr][d][hb(32)][ks(16)][gf(4)][lane(64)][e(8)] bf16
// arr=0: W[k][n], arr=1: U[k][n];  k = ks*32 + (lane>>4)*8 + e,
// n = gf*512 + hb*16 + (lane&15)
__global__ void prep_wu_k(const float* __restrict__ Wf, const float* __restrict__ Uf,
                          const float* __restrict__ Wb, const float* __restrict__ Ub,
                          unsigned short* __restrict__ wupk){
  const int tot = 2*2*32*16*4*64*8;  // 4,194,304
  for (int i = blockIdx.x*blockDim.x + threadIdx.x; i < tot; i += gridDim.x*blockDim.x){
    int e    = i & 7;
    int lane = (i >> 3) & 63;
    int gf   = (i >> 9) & 3;
    int ks   = (i >> 11) & 15;
    int hb   = (i >> 15) & 31;
    int d    = (i >> 20) & 1;
    int arr  = (i >> 21) & 1;
    int jl = lane & 15, q = lane >> 4;
    int n = gf*HH + hb*16 + jl;
    int k = ks*32 + q*8 + e;
    const float* src = arr ? (d ? Ub : Uf) : (d ? Wb : Wf);
    wupk[i] = f2bf(src[(size_t)k*G4 + n]);
  }
}

// bias_pk[d][hb(32)][gf(4)][jl(16)]
__global__ void prep_bias_k(const float* __restrict__ bf_, const float* __restrict__ bb_,
                            float* __restrict__ bias_pk){
  int i = blockIdx.x*blockDim.x + threadIdx.x;
  if (i < 2*32*4*16){
    int jl = i & 15;
    int gf = (i >> 4) & 3;
    int hb = (i >> 6) & 31;
    int d  = i >> 11;
    const float* src = d ? bb_ : bf_;
    bias_pk[i] = src[gf*HH + hb*16 + jl];
  }
}

// Wave-specialized persistent LSTM. 256 blocks x 256 thr (4 waves), 1 block/CU
// (147472B LDS), regular launch, grid == CU count -> all blocks resident.
// g = bid&7 -> (d, mq); hb = bid>>3 owns h-cols [hb*16, hb*16+16).
// Waves 0-1: recurrent chain, rows w*32..w*32+32, U from LDS, R5 LLC exchange
//            with per-wave flags (no intra-block barriers in the loop).
// Waves 2-3: x-GEMM producers (same rows), W from LDS, zx -> 2-deep LDS ring.
__global__ __launch_bounds__(256, 1)
void lstm_fused_k(const unsigned short* __restrict__ xtr,
                  const unsigned short* __restrict__ wupk,
                  const float* __restrict__ bias_pk,
                  unsigned short* hx,
                  int* flags,
                  float* __restrict__ out)
{
  __shared__ __align__(1024) unsigned short Wl[32768];   // 64KB [ks16][gf4][lane][8]
  __shared__ __align__(1024) unsigned short Ul[32768];   // 64KB [ks16][gf4][lane][8]
  __shared__ __align__(1024) int ringI[2][2][4][64][4];  // 16KB [par][w][grp][lane][4]
  __shared__ int xseq[2];
  __shared__ int cseq[2];

  const int tid  = threadIdx.x;
  const int lane = tid & 63;
  const int w    = tid >> 6;          // 0..3
  const int bid  = blockIdx.x;
  const int g    = bid & 7;
  const int hb   = bid >> 3;
  const int d    = g >> 2;
  const int mq   = g & 3;
  const int m0   = mq * 64;
  const int jl   = lane & 15, q = lane >> 4;

  // ---- stage W and U slices (linear fragment order, conflict-free reads) ----
  const unsigned short* wsrc = wupk + ((size_t)(0*2 + d)*32 + hb)*32768;
  const unsigned short* usrc = wupk + ((size_t)(1*2 + d)*32 + hb)*32768;
  for (int it = 0; it < 16; ++it){
    int u = it*256 + tid;
    __builtin_amdgcn_global_load_lds(
      (const __attribute__((address_space(1))) void*)(wsrc + (size_t)u*8),
      (__attribute__((address_space(3))) void*)(Wl + u*8), 16, 0, 0);
    __builtin_amdgcn_global_load_lds(
      (const __attribute__((address_space(1))) void*)(usrc + (size_t)u*8),
      (__attribute__((address_space(3))) void*)(Ul + u*8), 16, 0, 0);
  }
  if (tid < 2){ xseq[tid] = 0; cseq[tid] = 0; }
  __syncthreads();   // staging drained, seqs visible

  if (w >= 2){
    // ================= x-GEMM producer wave =================
    const int w2 = w - 2;
    float biasv[4];
    #pragma unroll
    for (int gf = 0; gf < 4; ++gf)
      biasv[gf] = bias_pk[((d*32 + hb)*4 + gf)*16 + jl];

    for (int s = 0; s < TT; ++s){
      const int t = d ? (TT-1-s) : s;
      if (s >= 2){
        while (__hip_atomic_load(&cseq[w2], __ATOMIC_ACQUIRE, __HIP_MEMORY_SCOPE_WORKGROUP) < s-1) {}
      }
      const unsigned short* xb = xtr + ((size_t)t*BB + m0 + w2*32)*DD;
      bf16x8 xa[2][16];
      #pragma unroll
      for (int ks = 0; ks < 16; ++ks)
        #pragma unroll
        for (int am = 0; am < 2; ++am)
          xa[am][ks] = *(const bf16x8*)(xb + (size_t)(am*16 + jl)*DD + ks*32 + q*8);

      f32x4 acc[2][4];
      #pragma unroll
      for (int am = 0; am < 2; ++am)
        #pragma unroll
        for (int gf = 0; gf < 4; ++gf){
          float bv = biasv[gf];
          acc[am][gf] = (f32x4){bv, bv, bv, bv};
        }

      #pragma unroll
      for (int ks = 0; ks < 16; ++ks){
        #pragma unroll
        for (int gf = 0; gf < 4; ++gf){
          bf16x8 b = *(const bf16x8*)(Wl + ((ks*4 + gf)*64 + lane)*8);
          #pragma unroll
          for (int am = 0; am < 2; ++am)
            acc[am][gf] = __builtin_amdgcn_mfma_f32_16x16x32_bf16(xa[am][ks], b, acc[am][gf], 0, 0, 0);
        }
      }

      const int slot = s & 1;
      #pragma unroll
      for (int am = 0; am < 2; ++am)
        #pragma unroll
        for (int gp = 0; gp < 2; ++gp){
          i32x4 pk;
          pk[0] = packbf(acc[am][gp*2  ][0], acc[am][gp*2  ][1]);
          pk[1] = packbf(acc[am][gp*2  ][2], acc[am][gp*2  ][3]);
          pk[2] = packbf(acc[am][gp*2+1][0], acc[am][gp*2+1][1]);
          pk[3] = packbf(acc[am][gp*2+1][2], acc[am][gp*2+1][3]);
          *(i32x4*)&ringI[slot][w2][am*2 + gp][lane][0] = pk;
        }
      __hip_atomic_store(&xseq[w2], s+1, __ATOMIC_RELEASE, __HIP_MEMORY_SCOPE_WORKGROUP);
    }
  } else {
    // ================= recurrent chain wave =================
    float cst[2][4];
    #pragma unroll
    for (int a = 0; a < 2; ++a)
      #pragma unroll
      for (int b = 0; b < 4; ++b) cst[a][b] = 0.f;
    int* myflags = flags + (g*2 + w)*64;   // 32 words used

    for (int s = 0; s < TT; ++s){
      const int t = d ? (TT-1-s) : s;

      // ---- zx from LDS ring (x-wave is normally ahead) ----
      while (__hip_atomic_load(&xseq[w], __ATOMIC_ACQUIRE, __HIP_MEMORY_SCOPE_WORKGROUP) < s+1) {}
      i32x4 zr[4];
      #pragma unroll
      for (int gi = 0; gi < 4; ++gi)
        zr[gi] = *(const i32x4*)&ringI[s&1][w][gi][lane][0];
      __hip_atomic_store(&cseq[w], s+1, __ATOMIC_RELEASE, __HIP_MEMORY_SCOPE_WORKGROUP);

      // ---- wait for the 32 producer-waves of this chain ----
      if (s > 0){
        for (;;){
          int v = (lane < 32)
            ? __hip_atomic_load(&myflags[lane], __ATOMIC_RELAXED, __HIP_MEMORY_SCOPE_AGENT)
            : s;
          if (__all(v >= s)) break;
          __builtin_amdgcn_s_sleep(1);
        }
      }
      asm volatile("" ::: "memory");

      // ---- h A-fragments (agent-scope, parity s&1) ----
      const unsigned short* hxg = hx + ((size_t)((g*2 + (s&1))*2 + w)*32)*512;
      union af_t { unsigned long long u[2]; bf16x8 v; } ha[2][16];
      #pragma unroll
      for (int ks = 0; ks < 16; ++ks){
        int chunk = ks*2 + (q >> 1);
        #pragma unroll
        for (int am = 0; am < 2; ++am){
          const unsigned long long* p = (const unsigned long long*)
              (hxg + (size_t)chunk*512 + (size_t)(am*16 + jl)*16 + (q&1)*8);
          ha[am][ks].u[0] = __hip_atomic_load(p,     __ATOMIC_RELAXED, __HIP_MEMORY_SCOPE_AGENT);
          ha[am][ks].u[1] = __hip_atomic_load(p + 1, __ATOMIC_RELAXED, __HIP_MEMORY_SCOPE_AGENT);
        }
      }

      f32x4 acc[2][4];
      #pragma unroll
      for (int am = 0; am < 2; ++am)
        #pragma unroll
        for (int gf = 0; gf < 4; ++gf) acc[am][gf] = (f32x4){0.f,0.f,0.f,0.f};

      #pragma unroll
      for (int ks = 0; ks < 16; ++ks){
        #pragma unroll
        for (int gf = 0; gf < 4; ++gf){
          bf16x8 b = *(const bf16x8*)(Ul + ((ks*4 + gf)*64 + lane)*8);
          #pragma unroll
          for (int am = 0; am < 2; ++am)
            acc[am][gf] = __builtin_amdgcn_mfma_f32_16x16x32_bf16(ha[am][ks].v, b, acc[am][gf], 0, 0, 0);
        }
      }

      // ---- epilogue: gates, c in regs; h stores FIRST, flag, then out ----
      unsigned short* hw = hx + (((size_t)((g*2 + ((s+1)&1))*2 + w)*32 + hb))*512;
      float hov[2][4];
      #pragma unroll
      for (int am = 0; am < 2; ++am){
        #pragma unroll
        for (int rr = 0; rr < 4; ++rr){
          float z[4];
          #pragma unroll
          for (int gf = 0; gf < 4; ++gf){
            int gi  = am*2 + (gf >> 1);
            int sel = (gf & 1)*2 + (rr >> 1);
            int sh  = (rr & 1)*16;
            int vv  = zr[gi][sel];
            z[gf] = acc[am][gf][rr] + bf2f((unsigned short)((vv >> sh) & 0xFFFF));
          }
          float i_ = sigf(z[0]);
          float f_ = sigf(z[1]);
          float g_ = tanhfast(z[2]);
          float o_ = sigf(z[3]);
          float c  = f_*cst[am][rr] + i_*g_;
          cst[am][rr] = c;
          float h = o_*tanhfast(c);
          hov[am][rr] = h;

          unsigned short h16 = f2bf(h);
          int other = __shfl_xor((int)h16, 1);
          if (!(jl & 1)){
            unsigned int pack = (unsigned int)h16 | (((unsigned int)other & 0xFFFFu) << 16);
            __hip_atomic_store((unsigned int*)(hw + (size_t)(am*16 + q*4 + rr)*16 + (jl & ~1)),
                               pack, __ATOMIC_RELAXED, __HIP_MEMORY_SCOPE_AGENT);
          }
        }
      }

      asm volatile("s_waitcnt vmcnt(0)" ::: "memory");  // h stores at coherence point
      if (lane == 0)
        __hip_atomic_store(&myflags[hb], s + 1, __ATOMIC_RELAXED, __HIP_MEMORY_SCOPE_AGENT);

      // out stores AFTER the flag (off the critical chain)
      #pragma unroll
      for (int am = 0; am < 2; ++am)
        #pragma unroll
        for (int rr = 0; rr < 4; ++rr){
          int b_ = m0 + w*32 + am*16 + q*4 + rr;
          out[((size_t)b_*TT + t)*(2*HH) + (size_t)d*HH + hb*16 + jl] = hov[am][rr];
        }
    }
  }
}

// sent_emb[b][n] = word_emb[b][T-1][n] (n<H) or word_emb[b][0][n] (n>=H)
__global__ void final_k(float* __restrict__ out){
  int i = blockIdx.x*blockDim.x + threadIdx.x;
  if (i < BB*2*HH){
    int b = i >> 10;
    int n = i & 1023;
    int t = (n < HH) ? (TT-1) : 0;
    out[(size_t)BB*TT*2*HH + i] = out[((size_t)b*TT + t)*2*HH + n];
  }
}

extern "C" void kernel_launch(void* const* d_in, const int* in_sizes, int n_in,
                              void* d_out, int out_size, void* d_ws, size_t ws_size,
                              hipStream_t stream)
{
  const float* x   = (const float*)d_in[0];
  const float* Wf  = (const float*)d_in[1];
  const float* Uf  = (const float*)d_in[2];
  const float* bf_ = (const float*)d_in[3];
  const float* Wb  = (const float*)d_in[4];
  const float* Ub  = (const float*)d_in[5];
  const float* bb_ = (const float*)d_in[6];
  float* out = (float*)d_out;

  char* ws = (char*)d_ws;
  unsigned short* xtr  = (unsigned short*)(ws);              // 33,554,432 B
  unsigned short* wupk = (unsigned short*)(ws + 33554432);   //  8,388,608 B
  float* bias_pk       = (float*)(ws + 41943040);            //     16,384 B
  unsigned short* hx   = (unsigned short*)(ws + 41959424);   //  4,194,304 B  [g8][par2][w2][hb32][row32][col16]
  int* flags           = (int*)(ws + 46153728);              //      4,096 B  [g8][w2][64]

  hipMemsetAsync(hx, 0, 4194304, stream);
  hipMemsetAsync(flags, 0, 4096, stream);

  prep_x_k   <<<2048, 256, 0, stream>>>(x, xtr);
  prep_wu_k  <<<4096, 256, 0, stream>>>(Wf, Uf, Wb, Ub, wupk);
  prep_bias_k<<<16,   256, 0, stream>>>(bf_, bb_, bias_pk);

  lstm_fused_k<<<256, 256, 0, stream>>>(xtr, wupk, bias_pk, hx, flags, out);

  final_k<<<1024, 256, 0, stream>>>(out);
}